// Round 5
// baseline (244.783 us; speedup 1.0000x reference)
//
#include <hip/hip_runtime.h>

namespace {

constexpr int B = 32;
constexpr int C = 512;
constexpr int N = 1024;
constexpr int R = 64;
constexpr float SCALE = 0.044194173824159216f; // 512^-0.5
constexpr float EPS = 1e-5f;

typedef float f32x4 __attribute__((ext_vector_type(4)));
typedef short bf16x8 __attribute__((ext_vector_type(8)));

__device__ __forceinline__ unsigned short f2b(float f) {
  union { unsigned int i; float f; } x;
  x.f = f;
  unsigned int v = x.i;
  return (unsigned short)((v + 0x7fffu + ((v >> 16) & 1u)) >> 16); // RNE
}

// XOR-swizzled byte address for the k1 x-tile: row stride 136 u16 (272 B).
__device__ __forceinline__ int xadr(int row, int ku16) {
  return (row * 272 + ku16 * 2) ^ (((row >> 3) & 7) << 4);
}

// ---------------------------------------------------------------------------
// K0: pre-swizzle weights into MFMA-fragment-linear bf16 layouts.
//  wtf/wpf/wgf: [rt(4)][kk(16)][lane(64)][e(8)]  from W[64][512]
//  wzf:         [ct(32)][kk(2)][lane(64)][e(8)]  from Wz[512][64]
// ---------------------------------------------------------------------------
__global__ __launch_bounds__(256) void k_prep(
    const float* __restrict__ Wt, const float* __restrict__ Wp,
    const float* __restrict__ Wg, const float* __restrict__ Wz,
    unsigned short* __restrict__ wtf, unsigned short* __restrict__ wpf,
    unsigned short* __restrict__ wgf, unsigned short* __restrict__ wzf)
{
  int i = blockIdx.x * 256 + (int)threadIdx.x; // 16384 threads
  int m = i >> 12, o = i & 4095;
  const float* src;
  unsigned short* dst;
  int sidx;
  if (m < 3) {
    int rt = o >> 10, kk = (o >> 6) & 15, l = o & 63;
    int r = rt * 16 + (l & 15), c = kk * 32 + (l >> 4) * 8;
    sidx = r * 512 + c;
    src = (m == 0) ? Wt : (m == 1) ? Wp : Wg;
    dst = (m == 0) ? wtf : (m == 1) ? wpf : wgf;
  } else {
    int ct = o >> 7, kk = (o >> 6) & 1, l = o & 63;
    int row = ct * 16 + (l & 15), k = kk * 32 + (l >> 4) * 8;
    sidx = row * 64 + k;
    src = Wz;
    dst = wzf;
  }
  float4 a = *(const float4*)(src + sidx);
  float4 bb = *(const float4*)(src + sidx + 4);
  ushort4 lo, hi;
  lo.x = f2b(a.x); lo.y = f2b(a.y); lo.z = f2b(a.z); lo.w = f2b(a.w);
  hi.x = f2b(bb.x); hi.y = f2b(bb.y); hi.z = f2b(bb.z); hi.w = f2b(bb.w);
  *(ushort4*)(dst + (size_t)o * 8) = lo;
  *(ushort4*)(dst + (size_t)o * 8 + 4) = hi;
}

// ---------------------------------------------------------------------------
// K1: MFMA projections, C-chunked (128) double-buffered.
//   t_s[b][n][r], p_s[b][n][r], g_s[b][r][n]   (bf16; SCALE folded into t)
// ---------------------------------------------------------------------------
__global__ __launch_bounds__(256) void k1_proj(
    const float* __restrict__ x,
    const unsigned short* __restrict__ wtf, const unsigned short* __restrict__ wpf,
    const unsigned short* __restrict__ wgf,
    const float* __restrict__ bt, const float* __restrict__ bp,
    const float* __restrict__ bg,
    unsigned short* __restrict__ t_s, unsigned short* __restrict__ p_s,
    unsigned short* __restrict__ g_s)
{
  __shared__ unsigned short xs[2][64 * 136]; // 2 x 17.4 KB

  const int b = blockIdx.y, n0 = blockIdx.x * 64;
  const int tid = (int)threadIdx.x, l = tid & 63, w = tid >> 6;
  const int col = l & 15, q = l >> 4;
  const int n4 = col * 4;
  const int c0a = w * 16 + q * 4;

  float4 v[2][4];
  auto issue = [&](int ch) {
    #pragma unroll
    for (int g = 0; g < 2; ++g) {
      int cb = ch * 128 + c0a + g * 64;
      #pragma unroll
      for (int i = 0; i < 4; ++i)
        v[g][i] = *(const float4*)(x + ((size_t)(b * C + cb + i) << 10) + n0 + n4);
    }
  };
  auto store = [&](int buf) {
    #pragma unroll
    for (int g = 0; g < 2; ++g) {
      int crel = c0a + g * 64;
      #pragma unroll
      for (int j = 0; j < 4; ++j) {
        unsigned int u0 = (unsigned int)f2b(((const float*)&v[g][0])[j]) |
                          ((unsigned int)f2b(((const float*)&v[g][1])[j]) << 16);
        unsigned int u1 = (unsigned int)f2b(((const float*)&v[g][2])[j]) |
                          ((unsigned int)f2b(((const float*)&v[g][3])[j]) << 16);
        uint2 val; val.x = u0; val.y = u1;
        *(uint2*)((char*)&xs[buf][0] + xadr(n4 + j, crel)) = val;
      }
    }
  };

  issue(0);
  store(0);
  __syncthreads();

  f32x4 tacc[4], pacc[4], gacc[4];
  #pragma unroll
  for (int i = 0; i < 4; ++i) {
    tacc[i] = (f32x4){0.f, 0.f, 0.f, 0.f};
    pacc[i] = (f32x4){0.f, 0.f, 0.f, 0.f};
    gacc[i] = (f32x4){0.f, 0.f, 0.f, 0.f};
  }

  int cur = 0;
  for (int ch = 0; ch < 4; ++ch) {
    if (ch < 3) issue(ch + 1);
    const char* xb = (const char*)&xs[cur][0];
    #pragma unroll
    for (int kk4 = 0; kk4 < 4; ++kk4) {
      int kkg = ch * 4 + kk4;
      bf16x8 aT = *(const bf16x8*)(xb + xadr(w * 16 + col, kk4 * 32 + q * 8));
      bf16x8 aG = *(const bf16x8*)(wgf + ((size_t)((w * 16 + kkg) * 64 + l) << 3));
      #pragma unroll
      for (int rt = 0; rt < 4; ++rt) {
        bf16x8 bT = *(const bf16x8*)(wtf + ((size_t)((rt * 16 + kkg) * 64 + l) << 3));
        tacc[rt] = __builtin_amdgcn_mfma_f32_16x16x32_bf16(aT, bT, tacc[rt], 0, 0, 0);
        bf16x8 bP = *(const bf16x8*)(wpf + ((size_t)((rt * 16 + kkg) * 64 + l) << 3));
        pacc[rt] = __builtin_amdgcn_mfma_f32_16x16x32_bf16(aT, bP, pacc[rt], 0, 0, 0);
        bf16x8 bG = *(const bf16x8*)(xb + xadr(rt * 16 + col, kk4 * 32 + q * 8));
        gacc[rt] = __builtin_amdgcn_mfma_f32_16x16x32_bf16(aG, bG, gacc[rt], 0, 0, 0);
      }
    }
    if (ch < 3) {
      __syncthreads();
      store(cur ^ 1);
      __syncthreads();
      cur ^= 1;
    }
  }

  // t/p: D row = n_loc, col = r_loc
  #pragma unroll
  for (int rt = 0; rt < 4; ++rt) {
    int r = rt * 16 + col;
    float btv = bt[r], bpv = bp[r];
    #pragma unroll
    for (int reg = 0; reg < 4; ++reg) {
      int n = n0 + w * 16 + q * 4 + reg;
      size_t o = (((size_t)b << 10) + n) * 64 + r;
      t_s[o] = f2b((tacc[rt][reg] + btv) * SCALE);
      p_s[o] = f2b(pacc[rt][reg] + bpv);
    }
  }
  // g: D row = r_loc, col = n_loc
  #pragma unroll
  for (int reg = 0; reg < 4; ++reg) {
    int r = w * 16 + q * 4 + reg;
    float bgv = bg[r];
    #pragma unroll
    for (int nt = 0; nt < 4; ++nt) {
      size_t o = (((size_t)b << 6) + r) * 1024 + n0 + nt * 16 + col;
      g_s[o] = f2b(gacc[nt][reg] + bgv);
    }
  }
}

// ---------------------------------------------------------------------------
// K2: barrier-free MFMA flash attention, KV-split x2.
// Fixed-max softmax (S ~ N(0,0.125)) -> partials combine linearly.
// Grid 1024 blocks: bid = (b>>3)*256 + (nq*2+split)*8 + (b&7)  (XCD-local batch)
// Each wave owns 16 q-rows; p/g fragments gathered straight from L2.
// Outputs: y_part[split][b][n][r] f32 (unnormalized), l_part[split][b][n] f32.
// ---------------------------------------------------------------------------
__global__ __launch_bounds__(256) void k2_attn(
    const unsigned short* __restrict__ t_s, const unsigned short* __restrict__ p_s,
    const unsigned short* __restrict__ g_s, float* __restrict__ y_part,
    float* __restrict__ l_part)
{
  __shared__ unsigned short pl[4][16 * 72]; // 9.2 KB

  const int bid = (int)blockIdx.x;
  const int br = bid & 7, nqs = (bid >> 3) & 31, bq = bid >> 8;
  const int b = bq * 8 + br;
  const int nq = nqs >> 1, split = nqs & 1;
  const int n0 = nq * 64;
  const int m0base = split * 512;

  const int tid = (int)threadIdx.x, l = tid & 63, w = tid >> 6;
  const int col = l & 15, q = l >> 4;

  bf16x8 qf[2];
  #pragma unroll
  for (int kk = 0; kk < 2; ++kk)
    qf[kk] = *(const bf16x8*)(t_s + (((size_t)b << 10) + n0 + w * 16 + col) * 64 +
                              kk * 32 + q * 8);

  f32x4 yacc[4];
  float lsum[4];
  #pragma unroll
  for (int i = 0; i < 4; ++i) {
    yacc[i] = (f32x4){0.f, 0.f, 0.f, 0.f};
    lsum[i] = 0.f;
  }

  unsigned short* plw = &pl[w][0];

  for (int mt = 0; mt < 8; ++mt) {
    const int m0 = m0base + mt * 64;

    f32x4 sacc[4];
    #pragma unroll
    for (int jt = 0; jt < 4; ++jt) {
      sacc[jt] = (f32x4){0.f, 0.f, 0.f, 0.f};
      #pragma unroll
      for (int kk = 0; kk < 2; ++kk) {
        bf16x8 pf = *(const bf16x8*)(p_s + (((size_t)b << 10) + m0 + jt * 16 + col) * 64 +
                                     kk * 32 + q * 8);
        sacc[jt] = __builtin_amdgcn_mfma_f32_16x16x32_bf16(qf[kk], pf, sacc[jt], 0, 0, 0);
      }
    }

    #pragma unroll
    for (int jt = 0; jt < 4; ++jt)
      #pragma unroll
      for (int reg = 0; reg < 4; ++reg) {
        float pv = __expf(sacc[jt][reg] - 3.0f);
        lsum[reg] += pv;
        plw[(q * 4 + reg) * 72 + jt * 16 + col] = f2b(pv);
      }

    bf16x8 paf[2];
    #pragma unroll
    for (int kj = 0; kj < 2; ++kj)
      paf[kj] = *(const bf16x8*)&plw[col * 72 + kj * 32 + q * 8];
    #pragma unroll
    for (int rt = 0; rt < 4; ++rt)
      #pragma unroll
      for (int kj = 0; kj < 2; ++kj) {
        bf16x8 gf = *(const bf16x8*)(g_s + (((size_t)b << 6) + rt * 16 + col) * 1024 +
                                     m0 + kj * 32 + q * 8);
        yacc[rt] = __builtin_amdgcn_mfma_f32_16x16x32_bf16(paf[kj], gf, yacc[rt], 0, 0, 0);
      }
  }

  const size_t ybase = ((size_t)(split * B + b) << 10);
  #pragma unroll
  for (int reg = 0; reg < 4; ++reg) {
    int n = n0 + w * 16 + q * 4 + reg;
    #pragma unroll
    for (int rt = 0; rt < 4; ++rt)
      y_part[(ybase + n) * 64 + rt * 16 + col] = yacc[rt][reg];
    float red = lsum[reg];
    red += __shfl_xor(red, 1);
    red += __shfl_xor(red, 2);
    red += __shfl_xor(red, 4);
    red += __shfl_xor(red, 8);
    if (col == 0) l_part[ybase + n] = red;
  }
}

// ---------------------------------------------------------------------------
// K3: combine partials (y = (y0+y1)/(l0+l1)) during LDS staging, then
// z = y.Wz^T + bz; BN; + x; f32 out. 64c x 256n per block.
// ---------------------------------------------------------------------------
__global__ __launch_bounds__(256) void k3_out(
    const float* __restrict__ y_part, const float* __restrict__ l_part,
    const unsigned short* __restrict__ wzf,
    const float* __restrict__ bz, const float* __restrict__ gma,
    const float* __restrict__ bet, const float* __restrict__ bmean,
    const float* __restrict__ bvar, const float* __restrict__ x,
    float* __restrict__ out)
{
  __shared__ unsigned short ys[256 * 72]; // 36.9 KB

  const int c0 = blockIdx.x * 64, n0 = blockIdx.y * 256, b = blockIdx.z;
  const int tid = (int)threadIdx.x, l = tid & 63, w = tid >> 6;
  const int col = l & 15, q = l >> 4;

  const float* y0 = y_part + (((size_t)b << 10)) * 64;
  const float* y1 = y_part + (((size_t)(B + b) << 10)) * 64;
  const float* l0 = l_part + ((size_t)b << 10);
  const float* l1 = l_part + ((size_t)(B + b) << 10);

  #pragma unroll
  for (int k = 0; k < 8; ++k) {
    int idx = tid + k * 256;
    int row = idx >> 3;
    int seg = (idx & 7) * 8;
    int n = n0 + row;
    float inv = 1.f / (l0[n] + l1[n]);
    const float* a0 = y0 + (size_t)n * 64 + seg;
    const float* a1 = y1 + (size_t)n * 64 + seg;
    float4 u0 = *(const float4*)a0;
    float4 u1 = *(const float4*)(a0 + 4);
    float4 v0 = *(const float4*)a1;
    float4 v1 = *(const float4*)(a1 + 4);
    uint4 pk;
    pk.x = (unsigned int)f2b((u0.x + v0.x) * inv) |
           ((unsigned int)f2b((u0.y + v0.y) * inv) << 16);
    pk.y = (unsigned int)f2b((u0.z + v0.z) * inv) |
           ((unsigned int)f2b((u0.w + v0.w) * inv) << 16);
    pk.z = (unsigned int)f2b((u1.x + v1.x) * inv) |
           ((unsigned int)f2b((u1.y + v1.y) * inv) << 16);
    pk.w = (unsigned int)f2b((u1.z + v1.z) * inv) |
           ((unsigned int)f2b((u1.w + v1.w) * inv) << 16);
    *(uint4*)&ys[row * 72 + seg] = pk;
  }
  __syncthreads();

  const int ct = (c0 >> 4) + w;
  bf16x8 aW0 = *(const bf16x8*)(wzf + ((size_t)((ct * 2 + 0) * 64 + l) << 3));
  bf16x8 aW1 = *(const bf16x8*)(wzf + ((size_t)((ct * 2 + 1) * 64 + l) << 3));

  f32x4 acc[16];
  #pragma unroll
  for (int i = 0; i < 16; ++i) acc[i] = (f32x4){0.f, 0.f, 0.f, 0.f};

  #pragma unroll
  for (int nt = 0; nt < 16; ++nt) {
    bf16x8 b0 = *(const bf16x8*)&ys[(nt * 16 + col) * 72 + q * 8];
    acc[nt] = __builtin_amdgcn_mfma_f32_16x16x32_bf16(aW0, b0, acc[nt], 0, 0, 0);
    bf16x8 b1 = *(const bf16x8*)&ys[(nt * 16 + col) * 72 + 32 + q * 8];
    acc[nt] = __builtin_amdgcn_mfma_f32_16x16x32_bf16(aW1, b1, acc[nt], 0, 0, 0);
  }

  #pragma unroll
  for (int reg = 0; reg < 4; ++reg) {
    int c = c0 + w * 16 + q * 4 + reg;
    float s = gma[c] * rsqrtf(bvar[c] + EPS);
    float a = (bz[c] - bmean[c]) * s + bet[c];
    #pragma unroll
    for (int nt = 0; nt < 16; ++nt) {
      size_t oi = ((size_t)(b * C + c) << 10) + n0 + nt * 16 + col;
      out[oi] = acc[nt][reg] * s + a + x[oi];
    }
  }
}

} // namespace

extern "C" void kernel_launch(void* const* d_in, const int* in_sizes, int n_in,
                              void* d_out, int out_size, void* d_ws, size_t ws_size,
                              hipStream_t stream)
{
  const float* x   = (const float*)d_in[0];
  const float* Wt  = (const float*)d_in[1];
  const float* bt  = (const float*)d_in[2];
  const float* Wp  = (const float*)d_in[3];
  const float* bp  = (const float*)d_in[4];
  const float* Wg  = (const float*)d_in[5];
  const float* bg  = (const float*)d_in[6];
  const float* Wz  = (const float*)d_in[7];
  const float* bz  = (const float*)d_in[8];
  const float* gma = (const float*)d_in[9];
  const float* bet = (const float*)d_in[10];
  const float* bmn = (const float*)d_in[11];
  const float* bvr = (const float*)d_in[12];
  float* out = (float*)d_out;

  unsigned short* base = (unsigned short*)d_ws;
  unsigned short* wtf = base;
  unsigned short* wpf = base + 32768;
  unsigned short* wgf = base + 65536;
  unsigned short* wzf = base + 98304;
  unsigned short* t_s = base + 131072;
  const size_t SZ = (size_t)B * N * R; // 2,097,152
  unsigned short* p_s = t_s + SZ;
  unsigned short* g_s = p_s + SZ;
  // f32 partials after the bf16 region (byte offset (131072 + 3*SZ)*2, 16B-aligned)
  float* y_part = (float*)(g_s + SZ);                 // 2 * SZ f32 = 16 MB
  float* l_part = y_part + 2 * SZ;                    // 2 * 32K f32

  k_prep<<<64, 256, 0, stream>>>(Wt, Wp, Wg, Wz, wtf, wpf, wgf, wzf);
  k1_proj<<<dim3(16, 32), 256, 0, stream>>>(x, wtf, wpf, wgf, bt, bp, bg,
                                            t_s, p_s, g_s);
  k2_attn<<<1024, 256, 0, stream>>>(t_s, p_s, g_s, y_part, l_part);
  k3_out<<<dim3(8, 4, 32), 256, 0, stream>>>(y_part, l_part, wzf, bz, gma, bet,
                                             bmn, bvr, x, out);
}

// Round 6
// 229.157 us; speedup vs baseline: 1.0682x; 1.0682x over previous
//
#include <hip/hip_runtime.h>

namespace {

constexpr int B = 32;
constexpr int C = 512;
constexpr int N = 1024;
constexpr int R = 64;
constexpr float SCALE = 0.044194173824159216f; // 512^-0.5
constexpr float EPS = 1e-5f;

typedef float f32x4 __attribute__((ext_vector_type(4)));
typedef short bf16x8 __attribute__((ext_vector_type(8)));

__device__ __forceinline__ unsigned short f2b(float f) {
  union { unsigned int i; float f; } x;
  x.f = f;
  unsigned int v = x.i;
  return (unsigned short)((v + 0x7fffu + ((v >> 16) & 1u)) >> 16); // RNE
}

// XOR-swizzled byte address for the k1 x-tile: row stride 136 u16 (272 B).
__device__ __forceinline__ int xadr(int row, int ku16) {
  return (row * 272 + ku16 * 2) ^ (((row >> 3) & 7) << 4);
}

// k2 LDS tiles: 64 rows x 128 B, XOR swizzle spreads rows across bank groups.
// Reads (16 consecutive rows, fixed 16B seg) -> 2-way (free). Writes
// (8 lanes = 1 row x 8 segs per phase) -> conflict-free.
__device__ __forceinline__ int sw128(int row, int byteInRow) {
  return (row * 128 + byteInRow) ^ ((row & 7) << 4);
}

// ---------------------------------------------------------------------------
// K0: pre-swizzle weights into MFMA-fragment-linear bf16 layouts.
//  wtf/wpf/wgf: [rt(4)][kk(16)][lane(64)][e(8)]  from W[64][512]
//  wzf:         [ct(32)][kk(2)][lane(64)][e(8)]  from Wz[512][64]
// ---------------------------------------------------------------------------
__global__ __launch_bounds__(256) void k_prep(
    const float* __restrict__ Wt, const float* __restrict__ Wp,
    const float* __restrict__ Wg, const float* __restrict__ Wz,
    unsigned short* __restrict__ wtf, unsigned short* __restrict__ wpf,
    unsigned short* __restrict__ wgf, unsigned short* __restrict__ wzf)
{
  int i = blockIdx.x * 256 + (int)threadIdx.x; // 16384 threads
  int m = i >> 12, o = i & 4095;
  const float* src;
  unsigned short* dst;
  int sidx;
  if (m < 3) {
    int rt = o >> 10, kk = (o >> 6) & 15, l = o & 63;
    int r = rt * 16 + (l & 15), c = kk * 32 + (l >> 4) * 8;
    sidx = r * 512 + c;
    src = (m == 0) ? Wt : (m == 1) ? Wp : Wg;
    dst = (m == 0) ? wtf : (m == 1) ? wpf : wgf;
  } else {
    int ct = o >> 7, kk = (o >> 6) & 1, l = o & 63;
    int row = ct * 16 + (l & 15), k = kk * 32 + (l >> 4) * 8;
    sidx = row * 64 + k;
    src = Wz;
    dst = wzf;
  }
  float4 a = *(const float4*)(src + sidx);
  float4 bb = *(const float4*)(src + sidx + 4);
  ushort4 lo, hi;
  lo.x = f2b(a.x); lo.y = f2b(a.y); lo.z = f2b(a.z); lo.w = f2b(a.w);
  hi.x = f2b(bb.x); hi.y = f2b(bb.y); hi.z = f2b(bb.z); hi.w = f2b(bb.w);
  *(ushort4*)(dst + (size_t)o * 8) = lo;
  *(ushort4*)(dst + (size_t)o * 8 + 4) = hi;
}

// ---------------------------------------------------------------------------
// K1: MFMA projections, C-chunked (128) double-buffered.
//   t_s[b][n][r], p_s[b][n][r], g_s[b][r][n]   (bf16; SCALE folded into t)
// ---------------------------------------------------------------------------
__global__ __launch_bounds__(256) void k1_proj(
    const float* __restrict__ x,
    const unsigned short* __restrict__ wtf, const unsigned short* __restrict__ wpf,
    const unsigned short* __restrict__ wgf,
    const float* __restrict__ bt, const float* __restrict__ bp,
    const float* __restrict__ bg,
    unsigned short* __restrict__ t_s, unsigned short* __restrict__ p_s,
    unsigned short* __restrict__ g_s)
{
  __shared__ unsigned short xs[2][64 * 136]; // 2 x 17.4 KB

  const int b = blockIdx.y, n0 = blockIdx.x * 64;
  const int tid = (int)threadIdx.x, l = tid & 63, w = tid >> 6;
  const int col = l & 15, q = l >> 4;
  const int n4 = col * 4;
  const int c0a = w * 16 + q * 4;

  float4 v[2][4];
  auto issue = [&](int ch) {
    #pragma unroll
    for (int g = 0; g < 2; ++g) {
      int cb = ch * 128 + c0a + g * 64;
      #pragma unroll
      for (int i = 0; i < 4; ++i)
        v[g][i] = *(const float4*)(x + ((size_t)(b * C + cb + i) << 10) + n0 + n4);
    }
  };
  auto store = [&](int buf) {
    #pragma unroll
    for (int g = 0; g < 2; ++g) {
      int crel = c0a + g * 64;
      #pragma unroll
      for (int j = 0; j < 4; ++j) {
        unsigned int u0 = (unsigned int)f2b(((const float*)&v[g][0])[j]) |
                          ((unsigned int)f2b(((const float*)&v[g][1])[j]) << 16);
        unsigned int u1 = (unsigned int)f2b(((const float*)&v[g][2])[j]) |
                          ((unsigned int)f2b(((const float*)&v[g][3])[j]) << 16);
        uint2 val; val.x = u0; val.y = u1;
        *(uint2*)((char*)&xs[buf][0] + xadr(n4 + j, crel)) = val;
      }
    }
  };

  issue(0);
  store(0);
  __syncthreads();

  f32x4 tacc[4], pacc[4], gacc[4];
  #pragma unroll
  for (int i = 0; i < 4; ++i) {
    tacc[i] = (f32x4){0.f, 0.f, 0.f, 0.f};
    pacc[i] = (f32x4){0.f, 0.f, 0.f, 0.f};
    gacc[i] = (f32x4){0.f, 0.f, 0.f, 0.f};
  }

  int cur = 0;
  for (int ch = 0; ch < 4; ++ch) {
    if (ch < 3) issue(ch + 1);
    const char* xb = (const char*)&xs[cur][0];
    #pragma unroll
    for (int kk4 = 0; kk4 < 4; ++kk4) {
      int kkg = ch * 4 + kk4;
      bf16x8 aT = *(const bf16x8*)(xb + xadr(w * 16 + col, kk4 * 32 + q * 8));
      bf16x8 aG = *(const bf16x8*)(wgf + ((size_t)((w * 16 + kkg) * 64 + l) << 3));
      #pragma unroll
      for (int rt = 0; rt < 4; ++rt) {
        bf16x8 bT = *(const bf16x8*)(wtf + ((size_t)((rt * 16 + kkg) * 64 + l) << 3));
        tacc[rt] = __builtin_amdgcn_mfma_f32_16x16x32_bf16(aT, bT, tacc[rt], 0, 0, 0);
        bf16x8 bP = *(const bf16x8*)(wpf + ((size_t)((rt * 16 + kkg) * 64 + l) << 3));
        pacc[rt] = __builtin_amdgcn_mfma_f32_16x16x32_bf16(aT, bP, pacc[rt], 0, 0, 0);
        bf16x8 bG = *(const bf16x8*)(xb + xadr(rt * 16 + col, kk4 * 32 + q * 8));
        gacc[rt] = __builtin_amdgcn_mfma_f32_16x16x32_bf16(aG, bG, gacc[rt], 0, 0, 0);
      }
    }
    if (ch < 3) {
      __syncthreads();
      store(cur ^ 1);
      __syncthreads();
      cur ^= 1;
    }
  }

  // t/p: D row = n_loc, col = r_loc
  #pragma unroll
  for (int rt = 0; rt < 4; ++rt) {
    int r = rt * 16 + col;
    float btv = bt[r], bpv = bp[r];
    #pragma unroll
    for (int reg = 0; reg < 4; ++reg) {
      int n = n0 + w * 16 + q * 4 + reg;
      size_t o = (((size_t)b << 10) + n) * 64 + r;
      t_s[o] = f2b((tacc[rt][reg] + btv) * SCALE);
      p_s[o] = f2b(pacc[rt][reg] + bpv);
    }
  }
  // g: D row = r_loc, col = n_loc
  #pragma unroll
  for (int reg = 0; reg < 4; ++reg) {
    int r = w * 16 + q * 4 + reg;
    float bgv = bg[r];
    #pragma unroll
    for (int nt = 0; nt < 4; ++nt) {
      size_t o = (((size_t)b << 6) + r) * 1024 + n0 + nt * 16 + col;
      g_s[o] = f2b(gacc[nt][reg] + bgv);
    }
  }
}

// ---------------------------------------------------------------------------
// K2: staged MFMA flash attention, KV-split x2, 40 KB LDS (4 blocks/CU).
// Fixed-max softmax (S ~ N(0,0.125) -> exp(S-3) safe); partials linear.
// Grid 1024: bid -> XCD-local batch (br = bid&7), nq/split inner.
// Outputs: y_part[split][b][n][r] f32 (unnormalized), l_part[split][b][n].
// ---------------------------------------------------------------------------
__global__ __launch_bounds__(256) void k2_attn(
    const unsigned short* __restrict__ t_s, const unsigned short* __restrict__ p_s,
    const unsigned short* __restrict__ g_s, float* __restrict__ y_part,
    float* __restrict__ l_part)
{
  __shared__ unsigned short ps[2][64 * 64]; // 16 KB
  __shared__ unsigned short gs[2][64 * 64]; // 16 KB
  __shared__ unsigned short pl[4][16 * 64]; //  8 KB  -> 40 KB total

  const int bid = (int)blockIdx.x;
  const int br = bid & 7, s = (bid >> 3) & 31, bq = bid >> 8;
  const int b = bq * 8 + br;
  const int nq = s >> 1, split = s & 1;
  const int n0 = nq * 64;
  const int m0base = split * 512;

  const int tid = (int)threadIdx.x, l = tid & 63, w = tid >> 6;
  const int col = l & 15, q = l >> 4;

  bf16x8 qf[2];
  #pragma unroll
  for (int kk = 0; kk < 2; ++kk)
    qf[kk] = *(const bf16x8*)(t_s + (((size_t)b << 10) + n0 + w * 16 + col) * 64 +
                              kk * 32 + q * 8);

  const int srow = tid >> 3;       // + k*32
  const int ssegB = (tid & 7) * 16; // byte seg within 128B row
  float4 ldp[2], ldg[2];
  auto issue = [&](int m0) {
    #pragma unroll
    for (int k = 0; k < 2; ++k) {
      int row = srow + k * 32;
      ldp[k] = *(const float4*)((const char*)p_s +
               ((((size_t)b << 10) + m0 + row) * 64) * 2 + ssegB);
      ldg[k] = *(const float4*)((const char*)g_s +
               ((((size_t)b << 6) + row) * 1024 + m0) * 2 + ssegB);
    }
  };
  auto store = [&](int buf) {
    #pragma unroll
    for (int k = 0; k < 2; ++k) {
      int row = srow + k * 32;
      *(float4*)((char*)&ps[buf][0] + sw128(row, ssegB)) = ldp[k];
      *(float4*)((char*)&gs[buf][0] + sw128(row, ssegB)) = ldg[k];
    }
  };

  f32x4 yacc[4];
  float lsum[4];
  #pragma unroll
  for (int i = 0; i < 4; ++i) {
    yacc[i] = (f32x4){0.f, 0.f, 0.f, 0.f};
    lsum[i] = 0.f;
  }

  char* plw = (char*)&pl[w][0];

  issue(m0base);
  store(0);
  __syncthreads();

  int cur = 0;
  for (int mt = 0; mt < 8; ++mt) {
    if (mt < 7) issue(m0base + (mt + 1) * 64);

    f32x4 sacc[4];
    #pragma unroll
    for (int jt = 0; jt < 4; ++jt) {
      sacc[jt] = (f32x4){0.f, 0.f, 0.f, 0.f};
      #pragma unroll
      for (int kk = 0; kk < 2; ++kk) {
        bf16x8 pf = *(const bf16x8*)((const char*)&ps[cur][0] +
                                     sw128(jt * 16 + col, kk * 64 + q * 16));
        sacc[jt] = __builtin_amdgcn_mfma_f32_16x16x32_bf16(qf[kk], pf, sacc[jt], 0, 0, 0);
      }
    }

    #pragma unroll
    for (int jt = 0; jt < 4; ++jt)
      #pragma unroll
      for (int reg = 0; reg < 4; ++reg) {
        float pv = __expf(sacc[jt][reg] - 3.0f);
        lsum[reg] += pv;
        *(unsigned short*)(plw + sw128(q * 4 + reg, jt * 32 + col * 2)) = f2b(pv);
      }

    bf16x8 paf[2];
    #pragma unroll
    for (int kj = 0; kj < 2; ++kj)
      paf[kj] = *(const bf16x8*)(plw + sw128(col, kj * 64 + q * 16));
    #pragma unroll
    for (int rt = 0; rt < 4; ++rt)
      #pragma unroll
      for (int kj = 0; kj < 2; ++kj) {
        bf16x8 gf = *(const bf16x8*)((const char*)&gs[cur][0] +
                                     sw128(rt * 16 + col, kj * 64 + q * 16));
        yacc[rt] = __builtin_amdgcn_mfma_f32_16x16x32_bf16(paf[kj], gf, yacc[rt], 0, 0, 0);
      }

    if (mt < 7) {
      __syncthreads();
      store(cur ^ 1);
      __syncthreads();
      cur ^= 1;
    }
  }

  const size_t ybase = ((size_t)(split * B + b) << 10);
  #pragma unroll
  for (int reg = 0; reg < 4; ++reg) {
    int n = n0 + w * 16 + q * 4 + reg;
    #pragma unroll
    for (int rt = 0; rt < 4; ++rt)
      y_part[(ybase + n) * 64 + rt * 16 + col] = yacc[rt][reg];
    float red = lsum[reg];
    red += __shfl_xor(red, 1);
    red += __shfl_xor(red, 2);
    red += __shfl_xor(red, 4);
    red += __shfl_xor(red, 8);
    if (col == 0) l_part[ybase + n] = red;
  }
}

// ---------------------------------------------------------------------------
// K3: combine partials (y = (y0+y1)/(l0+l1)) during LDS staging, then
// z = y.Wz^T + bz; BN; + x; f32 out. 64c x 256n per block.
// ---------------------------------------------------------------------------
__global__ __launch_bounds__(256) void k3_out(
    const float* __restrict__ y_part, const float* __restrict__ l_part,
    const unsigned short* __restrict__ wzf,
    const float* __restrict__ bz, const float* __restrict__ gma,
    const float* __restrict__ bet, const float* __restrict__ bmean,
    const float* __restrict__ bvar, const float* __restrict__ x,
    float* __restrict__ out)
{
  __shared__ unsigned short ys[256 * 72]; // 36.9 KB

  const int c0 = blockIdx.x * 64, n0 = blockIdx.y * 256, b = blockIdx.z;
  const int tid = (int)threadIdx.x, l = tid & 63, w = tid >> 6;
  const int col = l & 15, q = l >> 4;

  const float* y0 = y_part + (((size_t)b << 10)) * 64;
  const float* y1 = y_part + (((size_t)(B + b) << 10)) * 64;
  const float* l0 = l_part + ((size_t)b << 10);
  const float* l1 = l_part + ((size_t)(B + b) << 10);

  #pragma unroll
  for (int k = 0; k < 8; ++k) {
    int idx = tid + k * 256;
    int row = idx >> 3;
    int seg = (idx & 7) * 8;
    int n = n0 + row;
    float inv = 1.f / (l0[n] + l1[n]);
    const float* a0 = y0 + (size_t)n * 64 + seg;
    const float* a1 = y1 + (size_t)n * 64 + seg;
    float4 u0 = *(const float4*)a0;
    float4 u1 = *(const float4*)(a0 + 4);
    float4 v0 = *(const float4*)a1;
    float4 v1 = *(const float4*)(a1 + 4);
    uint4 pk;
    pk.x = (unsigned int)f2b((u0.x + v0.x) * inv) |
           ((unsigned int)f2b((u0.y + v0.y) * inv) << 16);
    pk.y = (unsigned int)f2b((u0.z + v0.z) * inv) |
           ((unsigned int)f2b((u0.w + v0.w) * inv) << 16);
    pk.z = (unsigned int)f2b((u1.x + v1.x) * inv) |
           ((unsigned int)f2b((u1.y + v1.y) * inv) << 16);
    pk.w = (unsigned int)f2b((u1.z + v1.z) * inv) |
           ((unsigned int)f2b((u1.w + v1.w) * inv) << 16);
    *(uint4*)&ys[row * 72 + seg] = pk;
  }
  __syncthreads();

  const int ct = (c0 >> 4) + w;
  bf16x8 aW0 = *(const bf16x8*)(wzf + ((size_t)((ct * 2 + 0) * 64 + l) << 3));
  bf16x8 aW1 = *(const bf16x8*)(wzf + ((size_t)((ct * 2 + 1) * 64 + l) << 3));

  f32x4 acc[16];
  #pragma unroll
  for (int i = 0; i < 16; ++i) acc[i] = (f32x4){0.f, 0.f, 0.f, 0.f};

  #pragma unroll
  for (int nt = 0; nt < 16; ++nt) {
    bf16x8 b0 = *(const bf16x8*)&ys[(nt * 16 + col) * 72 + q * 8];
    acc[nt] = __builtin_amdgcn_mfma_f32_16x16x32_bf16(aW0, b0, acc[nt], 0, 0, 0);
    bf16x8 b1 = *(const bf16x8*)&ys[(nt * 16 + col) * 72 + 32 + q * 8];
    acc[nt] = __builtin_amdgcn_mfma_f32_16x16x32_bf16(aW1, b1, acc[nt], 0, 0, 0);
  }

  #pragma unroll
  for (int reg = 0; reg < 4; ++reg) {
    int c = c0 + w * 16 + q * 4 + reg;
    float s = gma[c] * rsqrtf(bvar[c] + EPS);
    float a = (bz[c] - bmean[c]) * s + bet[c];
    #pragma unroll
    for (int nt = 0; nt < 16; ++nt) {
      size_t oi = ((size_t)(b * C + c) << 10) + n0 + nt * 16 + col;
      out[oi] = acc[nt][reg] * s + a + x[oi];
    }
  }
}

} // namespace

extern "C" void kernel_launch(void* const* d_in, const int* in_sizes, int n_in,
                              void* d_out, int out_size, void* d_ws, size_t ws_size,
                              hipStream_t stream)
{
  const float* x   = (const float*)d_in[0];
  const float* Wt  = (const float*)d_in[1];
  const float* bt  = (const float*)d_in[2];
  const float* Wp  = (const float*)d_in[3];
  const float* bp  = (const float*)d_in[4];
  const float* Wg  = (const float*)d_in[5];
  const float* bg  = (const float*)d_in[6];
  const float* Wz  = (const float*)d_in[7];
  const float* bz  = (const float*)d_in[8];
  const float* gma = (const float*)d_in[9];
  const float* bet = (const float*)d_in[10];
  const float* bmn = (const float*)d_in[11];
  const float* bvr = (const float*)d_in[12];
  float* out = (float*)d_out;

  unsigned short* base = (unsigned short*)d_ws;
  unsigned short* wtf = base;
  unsigned short* wpf = base + 32768;
  unsigned short* wgf = base + 65536;
  unsigned short* wzf = base + 98304;
  unsigned short* t_s = base + 131072;
  const size_t SZ = (size_t)B * N * R; // 2,097,152
  unsigned short* p_s = t_s + SZ;
  unsigned short* g_s = p_s + SZ;
  float* y_part = (float*)(g_s + SZ);                 // 2 * SZ f32 = 16 MB
  float* l_part = y_part + 2 * SZ;                    // 2 * 32K f32

  k_prep<<<64, 256, 0, stream>>>(Wt, Wp, Wg, Wz, wtf, wpf, wgf, wzf);
  k1_proj<<<dim3(16, 32), 256, 0, stream>>>(x, wtf, wpf, wgf, bt, bp, bg,
                                            t_s, p_s, g_s);
  k2_attn<<<1024, 256, 0, stream>>>(t_s, p_s, g_s, y_part, l_part);
  k3_out<<<dim3(8, 4, 32), 256, 0, stream>>>(y_part, l_part, wzf, bz, gma, bet,
                                             bmn, bvr, x, out);
}